// Round 1
// baseline (1868.664 us; speedup 1.0000x reference)
//
#include <hip/hip_runtime.h>
#include <math.h>

// Problem constants
#define NB 16
#define NR 2048
#define NC 81
#define NQ 65
#define ND 1024
#define NK 1024
#define NDET 100
#define CAP 32768          // per-image valid-candidate cap (expect ~7.4K)
#define HBINS 5184         // 64*81 >= 5121 used bins
#define BBC 4.135166556742356f  // log(1000/16) as f32

// Output layout (floats), concatenated in reference return order
#define O_BOX   0
#define O_SCORE (NB*NDET*4)                  // 6400
#define O_LABEL (O_SCORE + NB*NDET)          // 8000
#define O_QUANT (O_LABEL + NB*NDET)          // 9600
#define O_FEAT  (O_QUANT + NB*NDET)          // 11200
#define O_VALID (O_FEAT + (size_t)NB*NDET*ND) // 1649600

// Workspace layout (bytes)
#define WS_CNT   ((size_t)0)                          // NB ints (zeroed by memset)
#define WS_CAND  ((size_t)256)                        // NB*CAP u64
#define WS_QUANT (WS_CAND + (size_t)NB*CAP*8)         // NB*NR int
#define WS_SELM  (WS_QUANT + (size_t)NB*NR*4)         // NB*NK int
#define WS_SELS  (WS_SELM + (size_t)NB*NK*4)          // NB*NK float
#define WS_SELN  (WS_SELS + (size_t)NB*NK*4)          // NB int (pad 256)
#define WS_CB    (WS_SELN + 256)                      // NB*NK float4
#define WS_OB    (WS_CB + (size_t)NB*NK*16)           // NB*NK float4
#define WS_DETK  (WS_OB + (size_t)NB*NK*16)           // NB*NDET int

__device__ __forceinline__ float4 decode_box(float4 d, float pw, float ph,
                                             float pcx, float pcy) {
    float dx = d.x / 10.0f, dy = d.y / 10.0f;
    float dw = fminf(d.z / 5.0f, BBC), dh = fminf(d.w / 5.0f, BBC);
    float cx = dx * pw + pcx, cy = dy * ph + pcy;
    float w = expf(dw) * pw, h = expf(dh) * ph;
    float4 r;
    r.x = fminf(fmaxf(cx - 0.5f * w, 0.0f), 640.0f);
    r.y = fminf(fmaxf(cy - 0.5f * h, 0.0f), 640.0f);
    r.z = fminf(fmaxf(cx + 0.5f * w, 0.0f), 640.0f);
    r.w = fminf(fmaxf(cy + 0.5f * h, 0.0f), 640.0f);
    return r;
}

// Stage 1: one wave per (b,r) row. Softmax stats, quantity argmax, decode+filter,
// append valid candidates (key = score_bits<<32 | ~m) to per-image list.
__global__ __launch_bounds__(256) void k_stage1(
    const float* __restrict__ logits, const float* __restrict__ qlog,
    const float* __restrict__ reg, const float* __restrict__ props,
    unsigned long long* __restrict__ cand, int* __restrict__ cand_cnt,
    int* __restrict__ quant) {
    int wave = blockIdx.x * 4 + (threadIdx.x >> 6);
    int lane = threadIdx.x & 63;
    int b = wave >> 11;
    int r = wave & (NR - 1);

    const float* Lrow = logits + (size_t)wave * NC;
    float v0 = Lrow[lane];
    float v1 = (lane < NC - 64) ? Lrow[64 + lane] : -1e30f;
    float mx = fmaxf(v0, v1);
    #pragma unroll
    for (int o = 32; o; o >>= 1) mx = fmaxf(mx, __shfl_xor(mx, o));
    float e = expf(v0 - mx) + ((lane < NC - 64) ? expf(v1 - mx) : 0.0f);
    float sm = e;
    #pragma unroll
    for (int o = 32; o; o >>= 1) sm += __shfl_xor(sm, o);

    // quantity argmax (first-index tiebreak)
    const float* Qrow = qlog + (size_t)wave * NQ;
    float qv = Qrow[lane];
    int qi = lane;
    if (lane == 0) {
        float q64 = Qrow[64];
        if (q64 > qv) { qv = q64; qi = 64; }
    }
    #pragma unroll
    for (int o = 32; o; o >>= 1) {
        float ov = __shfl_xor(qv, o);
        int oi = __shfl_xor(qi, o);
        if (ov > qv || (ov == qv && oi < qi)) { qv = ov; qi = oi; }
    }
    if (lane == 0) quant[wave] = qi;

    const float* P = props + (size_t)wave * 4;
    float p0 = P[0], p1 = P[1], p2 = P[2], p3 = P[3];
    float pw = p2 - p0, ph = p3 - p1;
    float pcx = p0 + 0.5f * pw, pcy = p1 + 0.5f * ph;
    const float* G = reg + (size_t)wave * (NC * 4);

    #pragma unroll
    for (int pass = 0; pass < 2; ++pass) {
        int cc = lane + pass * 64;
        if (cc >= NC - 1) break;
        int c = cc + 1;
        float4 d = *(const float4*)(G + 4 * c);
        float4 bx = decode_box(d, pw, ph, pcx, pcy);
        float bw = bx.z - bx.x, bh = bx.w - bx.y;
        float p = expf(Lrow[c] - mx) / sm;
        if (p > 0.05f && bw >= 0.01f && bh >= 0.01f) {
            int m = r * 80 + cc;
            int pos = atomicAdd(&cand_cnt[b], 1);
            if (pos < CAP)
                cand[(size_t)b * CAP + pos] =
                    ((unsigned long long)__float_as_uint(p) << 32) |
                    (unsigned)(~(unsigned)m);
        }
    }
}

// Stage 2: per-image exact top-K (value desc, index asc) via histogram + bitonic sort.
__global__ __launch_bounds__(1024) void k_select(
    const unsigned long long* __restrict__ cand, const int* __restrict__ cand_cnt,
    int* __restrict__ sel_m, float* __restrict__ sel_s, int* __restrict__ sel_n) {
    __shared__ unsigned int hist[HBINS];
    __shared__ unsigned long long list[4096];
    __shared__ int s_cnt, s_bstar;
    int b = blockIdx.x, tid = threadIdx.x;
    int V = cand_cnt[b];
    if (V > CAP) V = CAP;
    const unsigned long long* cnd = cand + (size_t)b * CAP;

    for (int i = tid; i < HBINS; i += 1024) hist[i] = 0;
    if (tid == 0) { s_cnt = 0; s_bstar = 0; }
    __syncthreads();

    for (int i = tid; i < V; i += 1024) {
        unsigned bits = (unsigned)(cnd[i] >> 32);
        atomicAdd(&hist[(bits - 0x3D000000u) >> 13], 1u);
    }
    __syncthreads();

    if (tid < 64) {
        int lane = tid, base = lane * 81;
        unsigned partial = 0;
        for (int j = 0; j < 81; ++j) partial += hist[base + j];
        unsigned incl = partial;
        #pragma unroll
        for (int o = 1; o < 64; o <<= 1) {
            unsigned t = __shfl_up(incl, o);
            if (lane >= o) incl += t;
        }
        unsigned total = __shfl(incl, 63);
        unsigned suffix = total - incl;  // count in bins above my range
        if (suffix < NK && suffix + partial >= NK) {
            unsigned A = suffix;  // A(bb) walking down from top bin
            int bcross = base;
            for (int bb = base + 80; bb >= base; --bb) {
                unsigned An = A + hist[bb];
                if (An >= NK) { bcross = bb; break; }
                A = An;
            }
            s_bstar = bcross;
        }
    }
    __syncthreads();
    int bstar = s_bstar;

    for (int i = tid; i < V; i += 1024) {
        unsigned long long key = cnd[i];
        int bin = (int)(((unsigned)(key >> 32) - 0x3D000000u) >> 13);
        if (bin >= bstar) {
            int p = atomicAdd(&s_cnt, 1);
            if (p < 4096) list[p] = key;
        }
    }
    __syncthreads();
    int S = s_cnt;
    if (S > 4096) S = 4096;
    int n = 2;
    while (n < S) n <<= 1;
    for (int i = S + tid; i < n; i += 1024) list[i] = 0ull;
    __syncthreads();

    for (int k2 = 2; k2 <= n; k2 <<= 1)
        for (int j = k2 >> 1; j > 0; j >>= 1) {
            for (int i = tid; i < n; i += 1024) {
                int ixj = i ^ j;
                if (ixj > i) {
                    unsigned long long a = list[i], c = list[ixj];
                    bool descRegion = ((i & k2) == 0);
                    if ((a < c) == descRegion) { list[i] = c; list[ixj] = a; }
                }
            }
            __syncthreads();
        }

    int L = S < NK ? S : NK;
    for (int k = tid; k < L; k += 1024) {
        unsigned long long key = list[k];
        sel_m[b * NK + k] = (int)(~(unsigned)key);
        sel_s[b * NK + k] = __uint_as_float((unsigned)(key >> 32));
    }
    if (tid == 0) sel_n[b] = L;
}

// Stage 3: decode boxes only for selected candidates; store clipped (cb) and
// class-offset (ob) versions.
__global__ __launch_bounds__(256) void k_decode(
    const float* __restrict__ reg, const float* __restrict__ props,
    const int* __restrict__ sel_m, const int* __restrict__ sel_n,
    float4* __restrict__ cb, float4* __restrict__ ob) {
    int idx = blockIdx.x * 256 + threadIdx.x;
    int b = idx >> 10, k = idx & (NK - 1);
    if (k >= sel_n[b]) return;
    int m = sel_m[b * NK + k];
    int r = m / 80, c = m - r * 80 + 1;
    size_t row = (size_t)b * NR + r;
    const float* P = props + row * 4;
    float p0 = P[0], p1 = P[1], p2 = P[2], p3 = P[3];
    float pw = p2 - p0, ph = p3 - p1;
    float pcx = p0 + 0.5f * pw, pcy = p1 + 0.5f * ph;
    float4 d = *(const float4*)(reg + row * (NC * 4) + 4 * c);
    float4 bx = decode_box(d, pw, ph, pcx, pcy);
    cb[(size_t)b * NK + k] = bx;
    float off = (float)c * 641.0f;
    float4 o = {bx.x + off, bx.y + off, bx.z + off, bx.w + off};
    ob[(size_t)b * NK + k] = o;
}

__device__ __forceinline__ bool iou_gt(float4 a, float bx1, float by1, float bx2,
                                       float by2, float areaB) {
    float areaA = (a.z - a.x) * (a.w - a.y);
    float ltx = fmaxf(a.x, bx1), lty = fmaxf(a.y, by1);
    float rbx = fminf(a.z, bx2), rby = fminf(a.w, by2);
    float iw = fmaxf(rbx - ltx, 0.0f), ih = fmaxf(rby - lty, 0.0f);
    float inter = iw * ih;
    float iou = inter / (areaA + areaB - inter + 1e-9f);
    return iou > 0.5f;
}

// Stage 4: greedy NMS, one wave per image, accepted boxes distributed over lanes.
// Early-exit after NDET accepted (later survivors don't affect output).
__global__ __launch_bounds__(64) void k_nms(const float4* __restrict__ ob,
                                            const int* __restrict__ sel_n,
                                            int* __restrict__ det_k) {
    int b = blockIdx.x, lane = threadIdx.x;
    int n = sel_n[b];
    const float* obf = (const float*)(ob + (size_t)b * NK);
    float4 a0 = {0, 0, 0, 0}, a1 = {0, 0, 0, 0};
    int A = 0;
    int* dk = det_k + b * NDET;
    for (int i0 = 0; i0 < n && A < NDET; i0 += 16) {
        float wv = obf[i0 * 4 + lane];  // 16 boxes staged across the wave
        int tmax = (n - i0 < 16) ? (n - i0) : 16;
        for (int t = 0; t < tmax; ++t) {
            float bx1 = __shfl(wv, 4 * t + 0), by1 = __shfl(wv, 4 * t + 1);
            float bx2 = __shfl(wv, 4 * t + 2), by2 = __shfl(wv, 4 * t + 3);
            float areaB = (bx2 - bx1) * (by2 - by1);
            bool sup = (lane < A) && iou_gt(a0, bx1, by1, bx2, by2, areaB);
            sup |= (lane + 64 < A) && iou_gt(a1, bx1, by1, bx2, by2, areaB);
            if (!__any((int)sup)) {
                if (lane == (A & 63)) {
                    float4 nb = {bx1, by1, bx2, by2};
                    if (A < 64) a0 = nb; else a1 = nb;
                }
                if (lane == 0) dk[A] = i0 + t;
                ++A;
                if (A == NDET) break;
            }
        }
    }
    for (int d = A + lane; d < NDET; d += 64) dk[d] = -1;
}

// Stage 5: final gather + feature copy; writes every output element.
__global__ __launch_bounds__(256) void k_final(
    const float* __restrict__ feats, const int* __restrict__ quant,
    const int* __restrict__ sel_m, const float* __restrict__ sel_s,
    const float4* __restrict__ cb, const int* __restrict__ det_k,
    float* __restrict__ out) {
    int bd = blockIdx.x;
    int b = bd / NDET, d = bd - b * NDET;
    int t = threadIdx.x;
    int k = det_k[b * NDET + d];
    float4* of = (float4*)(out + O_FEAT + (size_t)bd * ND);
    if (k >= 0) {
        int m = sel_m[b * NK + k];
        int r = m / 80, c = m - r * 80 + 1;
        if (t == 0) {
            ((float4*)(out + O_BOX))[bd] = cb[(size_t)b * NK + k];
            out[O_SCORE + bd] = sel_s[b * NK + k];
            out[O_LABEL + bd] = (float)c;
            out[O_QUANT + bd] = (float)quant[b * NR + r];
            out[O_VALID + bd] = 1.0f;
        }
        const float4* f = (const float4*)(feats + ((size_t)b * NR + r) * ND);
        of[t] = f[t];
    } else {
        if (t == 0) {
            float4 z = {0, 0, 0, 0};
            ((float4*)(out + O_BOX))[bd] = z;
            out[O_SCORE + bd] = 0.0f;
            out[O_LABEL + bd] = 0.0f;
            out[O_QUANT + bd] = 0.0f;
            out[O_VALID + bd] = 0.0f;
        }
        float4 z = {0, 0, 0, 0};
        of[t] = z;
    }
}

extern "C" void kernel_launch(void* const* d_in, const int* in_sizes, int n_in,
                              void* d_out, int out_size, void* d_ws, size_t ws_size,
                              hipStream_t stream) {
    const float* logits = (const float*)d_in[0];
    const float* qlog   = (const float*)d_in[1];
    const float* feats  = (const float*)d_in[2];
    const float* reg    = (const float*)d_in[3];
    const float* props  = (const float*)d_in[4];
    float* out = (float*)d_out;
    char* ws = (char*)d_ws;

    int* cand_cnt = (int*)(ws + WS_CNT);
    unsigned long long* cand = (unsigned long long*)(ws + WS_CAND);
    int* quant = (int*)(ws + WS_QUANT);
    int* sel_m = (int*)(ws + WS_SELM);
    float* sel_s = (float*)(ws + WS_SELS);
    int* sel_n = (int*)(ws + WS_SELN);
    float4* cb = (float4*)(ws + WS_CB);
    float4* ob = (float4*)(ws + WS_OB);
    int* det_k = (int*)(ws + WS_DETK);

    hipMemsetAsync(cand_cnt, 0, 256, stream);
    k_stage1<<<NB * NR / 4, 256, 0, stream>>>(logits, qlog, reg, props, cand,
                                              cand_cnt, quant);
    k_select<<<NB, 1024, 0, stream>>>(cand, cand_cnt, sel_m, sel_s, sel_n);
    k_decode<<<NB * NK / 256, 256, 0, stream>>>(reg, props, sel_m, sel_n, cb, ob);
    k_nms<<<NB, 64, 0, stream>>>(ob, sel_n, det_k);
    k_final<<<NB * NDET, 256, 0, stream>>>(feats, quant, sel_m, sel_s, cb, det_k,
                                           out);
}

// Round 2
// 360.512 us; speedup vs baseline: 5.1834x; 5.1834x over previous
//
#include <hip/hip_runtime.h>
#include <math.h>

// Problem constants
#define NB 16
#define NR 2048
#define NC 81
#define NQ 65
#define ND 1024
#define NK 1024
#define NDET 100
#define CAP 32768          // per-image valid-candidate cap (expect ~7.4K)
#define HBINS 5184         // 64*81 >= 5121 used bins
#define BBC 4.135166556742356f  // log(1000/16) as f32

// Output layout (floats), concatenated in reference return order
#define O_BOX   0
#define O_SCORE (NB*NDET*4)                  // 6400
#define O_LABEL (O_SCORE + NB*NDET)          // 8000
#define O_QUANT (O_LABEL + NB*NDET)          // 9600
#define O_FEAT  (O_QUANT + NB*NDET)          // 11200
#define O_VALID (O_FEAT + (size_t)NB*NDET*ND) // 1649600

// Workspace layout (bytes)
#define WS_CNT   ((size_t)0)                          // NB ints (zeroed by memset)
#define WS_CAND  ((size_t)256)                        // NB*CAP u64
#define WS_QUANT (WS_CAND + (size_t)NB*CAP*8)         // NB*NR int
#define WS_SELM  (WS_QUANT + (size_t)NB*NR*4)         // NB*NK int
#define WS_SELS  (WS_SELM + (size_t)NB*NK*4)          // NB*NK float
#define WS_SELN  (WS_SELS + (size_t)NB*NK*4)          // NB int (pad 256)
#define WS_CB    (WS_SELN + 256)                      // NB*NK float4
#define WS_OB    (WS_CB + (size_t)NB*NK*16)           // NB*NK float4
#define WS_DETK  (WS_OB + (size_t)NB*NK*16)           // NB*NDET int

__device__ __forceinline__ float4 decode_box(float4 d, float pw, float ph,
                                             float pcx, float pcy) {
    float dx = d.x / 10.0f, dy = d.y / 10.0f;
    float dw = fminf(d.z / 5.0f, BBC), dh = fminf(d.w / 5.0f, BBC);
    float cx = dx * pw + pcx, cy = dy * ph + pcy;
    float w = expf(dw) * pw, h = expf(dh) * ph;
    float4 r;
    r.x = fminf(fmaxf(cx - 0.5f * w, 0.0f), 640.0f);
    r.y = fminf(fmaxf(cy - 0.5f * h, 0.0f), 640.0f);
    r.z = fminf(fmaxf(cx + 0.5f * w, 0.0f), 640.0f);
    r.w = fminf(fmaxf(cy + 0.5f * h, 0.0f), 640.0f);
    return r;
}

// Stage 1: one wave per (b,r) row, 4 rows (one image) per block.
// Candidates aggregate in an LDS list; ONE global atomic per block reserves a
// contiguous chunk in the per-image candidate array (kills the 16-address
// global-atomic serialization that made R1's stage1 latency-bound at 25 GB/s).
__global__ __launch_bounds__(256) void k_stage1(
    const float* __restrict__ logits, const float* __restrict__ qlog,
    const float* __restrict__ reg, const float* __restrict__ props,
    unsigned long long* __restrict__ cand, int* __restrict__ cand_cnt,
    int* __restrict__ quant) {
    __shared__ unsigned long long sl[320];  // max 4 rows x 80 classes
    __shared__ int scnt, sbase;
    int wave = blockIdx.x * 4 + (threadIdx.x >> 6);
    int lane = threadIdx.x & 63;
    int b = wave >> 11;
    int r = wave & (NR - 1);
    if (threadIdx.x == 0) scnt = 0;
    __syncthreads();

    const float* Lrow = logits + (size_t)wave * NC;
    float v0 = Lrow[lane];
    float v1 = (lane < NC - 64) ? Lrow[64 + lane] : -1e30f;
    float mx = fmaxf(v0, v1);
    #pragma unroll
    for (int o = 32; o; o >>= 1) mx = fmaxf(mx, __shfl_xor(mx, o));
    float e = expf(v0 - mx) + ((lane < NC - 64) ? expf(v1 - mx) : 0.0f);
    float sm = e;
    #pragma unroll
    for (int o = 32; o; o >>= 1) sm += __shfl_xor(sm, o);

    // quantity argmax (first-index tiebreak)
    const float* Qrow = qlog + (size_t)wave * NQ;
    float qv = Qrow[lane];
    int qi = lane;
    if (lane == 0) {
        float q64 = Qrow[64];
        if (q64 > qv) { qv = q64; qi = 64; }
    }
    #pragma unroll
    for (int o = 32; o; o >>= 1) {
        float ov = __shfl_xor(qv, o);
        int oi = __shfl_xor(qi, o);
        if (ov > qv || (ov == qv && oi < qi)) { qv = ov; qi = oi; }
    }
    if (lane == 0) quant[wave] = qi;

    const float* P = props + (size_t)wave * 4;
    float p0 = P[0], p1 = P[1], p2 = P[2], p3 = P[3];
    float pw = p2 - p0, ph = p3 - p1;
    float pcx = p0 + 0.5f * pw, pcy = p1 + 0.5f * ph;
    const float* G = reg + (size_t)wave * (NC * 4);

    #pragma unroll
    for (int pass = 0; pass < 2; ++pass) {
        int cc = lane + pass * 64;
        if (cc < NC - 1) {
            int c = cc + 1;
            float4 d = *(const float4*)(G + 4 * c);
            float4 bx = decode_box(d, pw, ph, pcx, pcy);
            float bw = bx.z - bx.x, bh = bx.w - bx.y;
            float p = expf(Lrow[c] - mx) / sm;
            if (p > 0.05f && bw >= 0.01f && bh >= 0.01f) {
                int m = r * 80 + cc;
                int pos = atomicAdd(&scnt, 1);  // LDS atomic — cheap
                sl[pos] = ((unsigned long long)__float_as_uint(p) << 32) |
                          (unsigned)(~(unsigned)m);
            }
        }
    }
    __syncthreads();
    if (threadIdx.x == 0) sbase = atomicAdd(&cand_cnt[b], scnt);
    __syncthreads();
    int base = sbase, n = scnt;
    for (int i = threadIdx.x; i < n; i += 256) {
        int pos = base + i;
        if (pos < CAP) cand[(size_t)b * CAP + pos] = sl[i];
    }
}

// Stage 2: per-image exact top-K (value desc, index asc) via histogram + bitonic sort.
__global__ __launch_bounds__(1024) void k_select(
    const unsigned long long* __restrict__ cand, const int* __restrict__ cand_cnt,
    int* __restrict__ sel_m, float* __restrict__ sel_s, int* __restrict__ sel_n) {
    __shared__ unsigned int hist[HBINS];
    __shared__ unsigned long long list[4096];
    __shared__ int s_cnt, s_bstar;
    int b = blockIdx.x, tid = threadIdx.x;
    int V = cand_cnt[b];
    if (V > CAP) V = CAP;
    const unsigned long long* cnd = cand + (size_t)b * CAP;

    for (int i = tid; i < HBINS; i += 1024) hist[i] = 0;
    if (tid == 0) { s_cnt = 0; s_bstar = 0; }
    __syncthreads();

    for (int i = tid; i < V; i += 1024) {
        unsigned bits = (unsigned)(cnd[i] >> 32);
        atomicAdd(&hist[(bits - 0x3D000000u) >> 13], 1u);
    }
    __syncthreads();

    if (tid < 64) {
        int lane = tid, base = lane * 81;
        unsigned partial = 0;
        for (int j = 0; j < 81; ++j) partial += hist[base + j];
        unsigned incl = partial;
        #pragma unroll
        for (int o = 1; o < 64; o <<= 1) {
            unsigned t = __shfl_up(incl, o);
            if (lane >= o) incl += t;
        }
        unsigned total = __shfl(incl, 63);
        unsigned suffix = total - incl;  // count in bins above my range
        if (suffix < NK && suffix + partial >= NK) {
            unsigned A = suffix;  // A(bb) walking down from top bin
            int bcross = base;
            for (int bb = base + 80; bb >= base; --bb) {
                unsigned An = A + hist[bb];
                if (An >= NK) { bcross = bb; break; }
                A = An;
            }
            s_bstar = bcross;
        }
    }
    __syncthreads();
    int bstar = s_bstar;

    for (int i = tid; i < V; i += 1024) {
        unsigned long long key = cnd[i];
        int bin = (int)(((unsigned)(key >> 32) - 0x3D000000u) >> 13);
        if (bin >= bstar) {
            int p = atomicAdd(&s_cnt, 1);
            if (p < 4096) list[p] = key;
        }
    }
    __syncthreads();
    int S = s_cnt;
    if (S > 4096) S = 4096;
    int n = 2;
    while (n < S) n <<= 1;
    for (int i = S + tid; i < n; i += 1024) list[i] = 0ull;
    __syncthreads();

    for (int k2 = 2; k2 <= n; k2 <<= 1)
        for (int j = k2 >> 1; j > 0; j >>= 1) {
            for (int i = tid; i < n; i += 1024) {
                int ixj = i ^ j;
                if (ixj > i) {
                    unsigned long long a = list[i], c = list[ixj];
                    bool descRegion = ((i & k2) == 0);
                    if ((a < c) == descRegion) { list[i] = c; list[ixj] = a; }
                }
            }
            __syncthreads();
        }

    int L = S < NK ? S : NK;
    for (int k = tid; k < L; k += 1024) {
        unsigned long long key = list[k];
        sel_m[b * NK + k] = (int)(~(unsigned)key);
        sel_s[b * NK + k] = __uint_as_float((unsigned)(key >> 32));
    }
    if (tid == 0) sel_n[b] = L;
}

// Stage 3: decode boxes only for selected candidates; store clipped (cb) and
// class-offset (ob) versions.
__global__ __launch_bounds__(256) void k_decode(
    const float* __restrict__ reg, const float* __restrict__ props,
    const int* __restrict__ sel_m, const int* __restrict__ sel_n,
    float4* __restrict__ cb, float4* __restrict__ ob) {
    int idx = blockIdx.x * 256 + threadIdx.x;
    int b = idx >> 10, k = idx & (NK - 1);
    if (k >= sel_n[b]) return;
    int m = sel_m[b * NK + k];
    int r = m / 80, c = m - r * 80 + 1;
    size_t row = (size_t)b * NR + r;
    const float* P = props + row * 4;
    float p0 = P[0], p1 = P[1], p2 = P[2], p3 = P[3];
    float pw = p2 - p0, ph = p3 - p1;
    float pcx = p0 + 0.5f * pw, pcy = p1 + 0.5f * ph;
    float4 d = *(const float4*)(reg + row * (NC * 4) + 4 * c);
    float4 bx = decode_box(d, pw, ph, pcx, pcy);
    cb[(size_t)b * NK + k] = bx;
    float off = (float)c * 641.0f;
    float4 o = {bx.x + off, bx.y + off, bx.z + off, bx.w + off};
    ob[(size_t)b * NK + k] = o;
}

__device__ __forceinline__ bool iou_gt(float4 a, float bx1, float by1, float bx2,
                                       float by2, float areaB) {
    float areaA = (a.z - a.x) * (a.w - a.y);
    float ltx = fmaxf(a.x, bx1), lty = fmaxf(a.y, by1);
    float rbx = fminf(a.z, bx2), rby = fminf(a.w, by2);
    float iw = fmaxf(rbx - ltx, 0.0f), ih = fmaxf(rby - lty, 0.0f);
    float inter = iw * ih;
    float iou = inter / (areaA + areaB - inter + 1e-9f);
    return iou > 0.5f;
}

// Stage 4: greedy NMS, one wave per image, accepted boxes distributed over lanes.
// Early-exit after NDET accepted (later survivors don't affect output).
__global__ __launch_bounds__(64) void k_nms(const float4* __restrict__ ob,
                                            const int* __restrict__ sel_n,
                                            int* __restrict__ det_k) {
    int b = blockIdx.x, lane = threadIdx.x;
    int n = sel_n[b];
    const float* obf = (const float*)(ob + (size_t)b * NK);
    float4 a0 = {0, 0, 0, 0}, a1 = {0, 0, 0, 0};
    int A = 0;
    int* dk = det_k + b * NDET;
    for (int i0 = 0; i0 < n && A < NDET; i0 += 16) {
        float wv = obf[i0 * 4 + lane];  // 16 boxes staged across the wave
        int tmax = (n - i0 < 16) ? (n - i0) : 16;
        for (int t = 0; t < tmax; ++t) {
            float bx1 = __shfl(wv, 4 * t + 0), by1 = __shfl(wv, 4 * t + 1);
            float bx2 = __shfl(wv, 4 * t + 2), by2 = __shfl(wv, 4 * t + 3);
            float areaB = (bx2 - bx1) * (by2 - by1);
            bool sup = (lane < A) && iou_gt(a0, bx1, by1, bx2, by2, areaB);
            sup |= (lane + 64 < A) && iou_gt(a1, bx1, by1, bx2, by2, areaB);
            if (!__any((int)sup)) {
                if (lane == (A & 63)) {
                    float4 nb = {bx1, by1, bx2, by2};
                    if (A < 64) a0 = nb; else a1 = nb;
                }
                if (lane == 0) dk[A] = i0 + t;
                ++A;
                if (A == NDET) break;
            }
        }
    }
    for (int d = A + lane; d < NDET; d += 64) dk[d] = -1;
}

// Stage 5: final gather + feature copy; writes every output element.
__global__ __launch_bounds__(256) void k_final(
    const float* __restrict__ feats, const int* __restrict__ quant,
    const int* __restrict__ sel_m, const float* __restrict__ sel_s,
    const float4* __restrict__ cb, const int* __restrict__ det_k,
    float* __restrict__ out) {
    int bd = blockIdx.x;
    int b = bd / NDET, d = bd - b * NDET;
    int t = threadIdx.x;
    int k = det_k[b * NDET + d];
    float4* of = (float4*)(out + O_FEAT + (size_t)bd * ND);
    if (k >= 0) {
        int m = sel_m[b * NK + k];
        int r = m / 80, c = m - r * 80 + 1;
        if (t == 0) {
            ((float4*)(out + O_BOX))[bd] = cb[(size_t)b * NK + k];
            out[O_SCORE + bd] = sel_s[b * NK + k];
            out[O_LABEL + bd] = (float)c;
            out[O_QUANT + bd] = (float)quant[b * NR + r];
            out[O_VALID + bd] = 1.0f;
        }
        const float4* f = (const float4*)(feats + ((size_t)b * NR + r) * ND);
        of[t] = f[t];
    } else {
        if (t == 0) {
            float4 z = {0, 0, 0, 0};
            ((float4*)(out + O_BOX))[bd] = z;
            out[O_SCORE + bd] = 0.0f;
            out[O_LABEL + bd] = 0.0f;
            out[O_QUANT + bd] = 0.0f;
            out[O_VALID + bd] = 0.0f;
        }
        float4 z = {0, 0, 0, 0};
        of[t] = z;
    }
}

extern "C" void kernel_launch(void* const* d_in, const int* in_sizes, int n_in,
                              void* d_out, int out_size, void* d_ws, size_t ws_size,
                              hipStream_t stream) {
    const float* logits = (const float*)d_in[0];
    const float* qlog   = (const float*)d_in[1];
    const float* feats  = (const float*)d_in[2];
    const float* reg    = (const float*)d_in[3];
    const float* props  = (const float*)d_in[4];
    float* out = (float*)d_out;
    char* ws = (char*)d_ws;

    int* cand_cnt = (int*)(ws + WS_CNT);
    unsigned long long* cand = (unsigned long long*)(ws + WS_CAND);
    int* quant = (int*)(ws + WS_QUANT);
    int* sel_m = (int*)(ws + WS_SELM);
    float* sel_s = (float*)(ws + WS_SELS);
    int* sel_n = (int*)(ws + WS_SELN);
    float4* cb = (float4*)(ws + WS_CB);
    float4* ob = (float4*)(ws + WS_OB);
    int* det_k = (int*)(ws + WS_DETK);

    hipMemsetAsync(cand_cnt, 0, 256, stream);
    k_stage1<<<NB * NR / 4, 256, 0, stream>>>(logits, qlog, reg, props, cand,
                                              cand_cnt, quant);
    k_select<<<NB, 1024, 0, stream>>>(cand, cand_cnt, sel_m, sel_s, sel_n);
    k_decode<<<NB * NK / 256, 256, 0, stream>>>(reg, props, sel_m, sel_n, cb, ob);
    k_nms<<<NB, 64, 0, stream>>>(ob, sel_n, det_k);
    k_final<<<NB * NDET, 256, 0, stream>>>(feats, quant, sel_m, sel_s, cb, det_k,
                                           out);
}

// Round 3
// 304.650 us; speedup vs baseline: 6.1338x; 1.1834x over previous
//
#include <hip/hip_runtime.h>
#include <math.h>

// Problem constants
#define NB 16
#define NR 2048
#define NC 81
#define NQ 65
#define ND 1024
#define NK 1024
#define NDET 100
#define NBLK 512           // stage1 blocks per image (4 rows each)
#define BSLOT 64           // candidate slots per stage1 block (expect ~18, Poisson tail @64 ~1e-17)
#define HBINS 5184         // 64*81 >= 5121 used bins
#define BBC 4.135166556742356f  // log(1000/16) as f32

// Output layout (floats), concatenated in reference return order
#define O_BOX   0
#define O_SCORE (NB*NDET*4)
#define O_LABEL (O_SCORE + NB*NDET)
#define O_QUANT (O_LABEL + NB*NDET)
#define O_FEAT  (O_QUANT + NB*NDET)
#define O_VALID (O_FEAT + (size_t)NB*NDET*ND)

// Workspace layout (bytes) — no zeroing required anywhere (every field written each launch)
#define WS_CAND  ((size_t)0)                          // NB*NBLK*BSLOT u64 = 4 MB
#define WS_CNT   (WS_CAND + (size_t)NB*NBLK*BSLOT*8)  // NB*NBLK int = 32 KB
#define WS_QUANT (WS_CNT + (size_t)NB*NBLK*4)         // NB*NR int
#define WS_SELM  (WS_QUANT + (size_t)NB*NR*4)         // NB*NK int
#define WS_SELS  (WS_SELM + (size_t)NB*NK*4)          // NB*NK float
#define WS_CB    (WS_SELS + (size_t)NB*NK*4)          // NB*NK float4
#define WS_DETK  (WS_CB + (size_t)NB*NK*16)           // NB*NDET int

__device__ __forceinline__ float4 decode_box(float4 d, float pw, float ph,
                                             float pcx, float pcy) {
    float dx = d.x / 10.0f, dy = d.y / 10.0f;
    float dw = fminf(d.z / 5.0f, BBC), dh = fminf(d.w / 5.0f, BBC);
    float cx = dx * pw + pcx, cy = dy * ph + pcy;
    float w = expf(dw) * pw, h = expf(dh) * ph;
    float4 r;
    r.x = fminf(fmaxf(cx - 0.5f * w, 0.0f), 640.0f);
    r.y = fminf(fmaxf(cy - 0.5f * h, 0.0f), 640.0f);
    r.z = fminf(fmaxf(cx + 0.5f * w, 0.0f), 640.0f);
    r.w = fminf(fmaxf(cy + 0.5f * h, 0.0f), 640.0f);
    return r;
}

// Stage 1: one wave per row, 4 rows per block. ZERO global atomics: each block
// owns a deterministic 64-slot region (R2 showed the chunk-reserving global
// atomic serialized 512 blocks/image at ~200ns each = the whole 103us).
// Lazy expf: a candidate needs logit > mx + log(0.05*sm); only survivors
// (~4.4/row) load box_regression and run decode (42.5MB -> ~2MB of reg reads).
__global__ __launch_bounds__(256) void k_stage1(
    const float* __restrict__ logits, const float* __restrict__ qlog,
    const float* __restrict__ reg, const float* __restrict__ props,
    unsigned long long* __restrict__ cand, int* __restrict__ cnt,
    int* __restrict__ quant) {
    __shared__ unsigned long long sl[BSLOT];
    __shared__ int scnt;
    int b = blockIdx.x >> 9;
    int blk = blockIdx.x & (NBLK - 1);
    int wid = threadIdx.x >> 6;
    int lane = threadIdx.x & 63;
    int r = blk * 4 + wid;
    int row = b * NR + r;
    if (threadIdx.x == 0) scnt = 0;
    __syncthreads();

    const float* Lrow = logits + (size_t)row * NC;
    float v0 = Lrow[lane];
    float v1 = (lane < NC - 64) ? Lrow[64 + lane] : -1e30f;
    float mx = fmaxf(v0, v1);
    #pragma unroll
    for (int o = 32; o; o >>= 1) mx = fmaxf(mx, __shfl_xor(mx, o));
    float e = expf(v0 - mx) + ((lane < NC - 64) ? expf(v1 - mx) : 0.0f);
    float sm = e;
    #pragma unroll
    for (int o = 32; o; o >>= 1) sm += __shfl_xor(sm, o);
    // conservative logit-space threshold (margin >> logf ulp error); exact
    // p>0.05 re-check below for the few survivors
    float thr_lo = mx + logf(0.05f * sm) - 0.01f;

    // quantity argmax (first-index tiebreak)
    const float* Qrow = qlog + (size_t)row * NQ;
    float qv = Qrow[lane];
    int qi = lane;
    if (lane == 0) {
        float q64 = Qrow[64];
        if (q64 > qv) { qv = q64; qi = 64; }
    }
    #pragma unroll
    for (int o = 32; o; o >>= 1) {
        float ov = __shfl_xor(qv, o);
        int oi = __shfl_xor(qi, o);
        if (ov > qv || (ov == qv && oi < qi)) { qv = ov; qi = oi; }
    }
    if (lane == 0) quant[row] = qi;

    const float* P = props + (size_t)row * 4;
    float p0 = P[0], p1 = P[1], p2 = P[2], p3 = P[3];
    float pw = p2 - p0, ph = p3 - p1;
    float pcx = p0 + 0.5f * pw, pcy = p1 + 0.5f * ph;
    const float* G = reg + (size_t)row * (NC * 4);

    #pragma unroll
    for (int pass = 0; pass < 2; ++pass) {
        int cc = lane + pass * 64;
        if (cc < NC - 1) {
            int c = cc + 1;
            float lc = Lrow[c];
            if (lc > thr_lo) {
                float p = expf(lc - mx) / sm;          // exact, matches reference
                float4 d = *(const float4*)(G + 4 * c);
                float4 bx = decode_box(d, pw, ph, pcx, pcy);
                float bw = bx.z - bx.x, bh = bx.w - bx.y;
                if (p > 0.05f && bw >= 0.01f && bh >= 0.01f) {
                    int m = r * 80 + cc;
                    int pos = atomicAdd(&scnt, 1);     // LDS atomic, cheap
                    if (pos < BSLOT)
                        sl[pos] = ((unsigned long long)__float_as_uint(p) << 32) |
                                  (unsigned)(~(unsigned)m);
                }
            }
        }
    }
    __syncthreads();
    int n = scnt < BSLOT ? scnt : BSLOT;
    unsigned long long* dst = cand + ((size_t)b * NBLK + blk) * BSLOT;
    for (int i = threadIdx.x; i < n; i += 256) dst[i] = sl[i];
    if (threadIdx.x == 0) cnt[b * NBLK + blk] = n;
}

// Fused stage 2-4: per-image top-K (histogram cut + bitonic sort, exact
// value-desc/index-asc top_k semantics) + decode of selected + greedy NMS.
// One 1024-thread block per image.
__global__ __launch_bounds__(1024) void k_fused(
    const unsigned long long* __restrict__ cand, const int* __restrict__ cnt,
    const float* __restrict__ reg, const float* __restrict__ props,
    int* __restrict__ sel_m, float* __restrict__ sel_s,
    float4* __restrict__ cb, int* __restrict__ det_k) {
    __shared__ unsigned int hist[HBINS];        // ~20.7 KB
    __shared__ unsigned long long list[2048];   // 16 KB
    __shared__ float4 boxes[NK];                // 16 KB (class-offset boxes for NMS)
    __shared__ int scn[NBLK];                   // 2 KB
    __shared__ int s_cnt, s_bstar, s_n;
    int b = blockIdx.x, tid = threadIdx.x;
    const unsigned long long* cnd = cand + (size_t)b * NBLK * BSLOT;

    for (int i = tid; i < HBINS; i += 1024) hist[i] = 0;
    if (tid < NBLK) scn[tid] = cnt[b * NBLK + tid];
    if (tid == 0) { s_cnt = 0; s_bstar = 0; }
    __syncthreads();

    // histogram over sparse per-block slot regions
    for (int i = tid; i < NBLK * BSLOT; i += 1024) {
        if ((i & (BSLOT - 1)) < scn[i >> 6]) {
            unsigned bits = (unsigned)(cnd[i] >> 32);
            atomicAdd(&hist[(bits - 0x3D000000u) >> 13], 1u);
        }
    }
    __syncthreads();

    // find cut bin: smallest bin index such that count(bins >= it) >= NK
    if (tid < 64) {
        int lane = tid, base = lane * 81;
        unsigned partial = 0;
        for (int j = 0; j < 81; ++j) partial += hist[base + j];
        unsigned incl = partial;
        #pragma unroll
        for (int o = 1; o < 64; o <<= 1) {
            unsigned t = __shfl_up(incl, o);
            if (lane >= o) incl += t;
        }
        unsigned total = __shfl(incl, 63);
        unsigned suffix = total - incl;
        if (suffix < NK && suffix + partial >= NK) {
            unsigned A = suffix;
            int bcross = base;
            for (int bb = base + 80; bb >= base; --bb) {
                unsigned An = A + hist[bb];
                if (An >= NK) { bcross = bb; break; }
                A = An;
            }
            s_bstar = bcross;
        }
    }
    __syncthreads();
    int bstar = s_bstar;

    // collect keys in bins >= cut (S ~ NK + one bin's load <= ~1100)
    for (int i = tid; i < NBLK * BSLOT; i += 1024) {
        if ((i & (BSLOT - 1)) < scn[i >> 6]) {
            unsigned long long key = cnd[i];
            int bin = (int)(((unsigned)(key >> 32) - 0x3D000000u) >> 13);
            if (bin >= bstar) {
                int p = atomicAdd(&s_cnt, 1);
                if (p < 2048) list[p] = key;
            }
        }
    }
    __syncthreads();
    int S = s_cnt;
    if (S > 2048) S = 2048;
    int n = 2;
    while (n < S) n <<= 1;
    for (int i = S + tid; i < n; i += 1024) list[i] = 0ull;
    __syncthreads();

    for (int k2 = 2; k2 <= n; k2 <<= 1)
        for (int j = k2 >> 1; j > 0; j >>= 1) {
            for (int i = tid; i < n; i += 1024) {
                int ixj = i ^ j;
                if (ixj > i) {
                    unsigned long long a = list[i], c = list[ixj];
                    bool descRegion = ((i & k2) == 0);
                    if ((a < c) == descRegion) { list[i] = c; list[ixj] = a; }
                }
            }
            __syncthreads();
        }

    int L = S < NK ? S : NK;
    if (tid == 0) s_n = L;
    // decode selected candidates; clipped box -> global (output), offset box -> LDS (NMS)
    if (tid < L) {
        unsigned long long key = list[tid];
        int m = (int)(~(unsigned)key);
        sel_m[b * NK + tid] = m;
        sel_s[b * NK + tid] = __uint_as_float((unsigned)(key >> 32));
        int r = m / 80, c = m - r * 80 + 1;
        size_t row = (size_t)b * NR + r;
        const float* P = props + row * 4;
        float p0 = P[0], p1 = P[1], p2 = P[2], p3 = P[3];
        float pw = p2 - p0, ph = p3 - p1;
        float pcx = p0 + 0.5f * pw, pcy = p1 + 0.5f * ph;
        float4 d = *(const float4*)(reg + row * (NC * 4) + 4 * c);
        float4 bx = decode_box(d, pw, ph, pcx, pcy);
        cb[(size_t)b * NK + tid] = bx;
        float off = (float)c * 641.0f;
        float4 o = {bx.x + off, bx.y + off, bx.z + off, bx.w + off};
        boxes[tid] = o;
    }
    __syncthreads();

    // greedy NMS on wave 0; accepted boxes live in lanes; early-exit at NDET.
    if (tid < 64) {
        int lane = tid, nn = s_n, A = 0;
        float4 a0 = {0, 0, 0, 0}, a1 = {0, 0, 0, 0};
        int* dk = det_k + b * NDET;
        float4 nxt = (nn > 0) ? boxes[0] : a0;
        for (int t = 0; t < nn && A < NDET; ++t) {
            float4 bt = nxt;
            if (t + 1 < nn) nxt = boxes[t + 1];   // prefetch hides LDS latency
            float areaB = (bt.z - bt.x) * (bt.w - bt.y);
            float areaA0 = (a0.z - a0.x) * (a0.w - a0.y);
            float ltx = fmaxf(a0.x, bt.x), lty = fmaxf(a0.y, bt.y);
            float rbx = fminf(a0.z, bt.z), rby = fminf(a0.w, bt.w);
            float inter = fmaxf(rbx - ltx, 0.0f) * fmaxf(rby - lty, 0.0f);
            bool sup = (lane < A) &&
                       (inter / (areaA0 + areaB - inter + 1e-9f) > 0.5f);
            if (A > 64) {
                float areaA1 = (a1.z - a1.x) * (a1.w - a1.y);
                float ltx1 = fmaxf(a1.x, bt.x), lty1 = fmaxf(a1.y, bt.y);
                float rbx1 = fminf(a1.z, bt.z), rby1 = fminf(a1.w, bt.w);
                float in1 = fmaxf(rbx1 - ltx1, 0.0f) * fmaxf(rby1 - lty1, 0.0f);
                sup |= (lane + 64 < A) &&
                       (in1 / (areaA1 + areaB - in1 + 1e-9f) > 0.5f);
            }
            if (!__any((int)sup)) {
                if (lane == (A & 63)) {
                    if (A < 64) a0 = bt; else a1 = bt;
                }
                if (lane == 0) dk[A] = t;
                ++A;
            }
        }
        for (int d = A + lane; d < NDET; d += 64) dk[d] = -1;
    }
}

// Stage 5: final gather + feature copy; writes every output element.
__global__ __launch_bounds__(256) void k_final(
    const float* __restrict__ feats, const int* __restrict__ quant,
    const int* __restrict__ sel_m, const float* __restrict__ sel_s,
    const float4* __restrict__ cb, const int* __restrict__ det_k,
    float* __restrict__ out) {
    int bd = blockIdx.x;
    int b = bd / NDET, d = bd - b * NDET;
    int t = threadIdx.x;
    int k = det_k[b * NDET + d];
    float4* of = (float4*)(out + O_FEAT + (size_t)bd * ND);
    if (k >= 0) {
        int m = sel_m[b * NK + k];
        int r = m / 80, c = m - r * 80 + 1;
        if (t == 0) {
            ((float4*)(out + O_BOX))[bd] = cb[(size_t)b * NK + k];
            out[O_SCORE + bd] = sel_s[b * NK + k];
            out[O_LABEL + bd] = (float)c;
            out[O_QUANT + bd] = (float)quant[b * NR + r];
            out[O_VALID + bd] = 1.0f;
        }
        const float4* f = (const float4*)(feats + ((size_t)b * NR + r) * ND);
        of[t] = f[t];
    } else {
        if (t == 0) {
            float4 z = {0, 0, 0, 0};
            ((float4*)(out + O_BOX))[bd] = z;
            out[O_SCORE + bd] = 0.0f;
            out[O_LABEL + bd] = 0.0f;
            out[O_QUANT + bd] = 0.0f;
            out[O_VALID + bd] = 0.0f;
        }
        float4 z = {0, 0, 0, 0};
        of[t] = z;
    }
}

extern "C" void kernel_launch(void* const* d_in, const int* in_sizes, int n_in,
                              void* d_out, int out_size, void* d_ws, size_t ws_size,
                              hipStream_t stream) {
    const float* logits = (const float*)d_in[0];
    const float* qlog   = (const float*)d_in[1];
    const float* feats  = (const float*)d_in[2];
    const float* reg    = (const float*)d_in[3];
    const float* props  = (const float*)d_in[4];
    float* out = (float*)d_out;
    char* ws = (char*)d_ws;

    unsigned long long* cand = (unsigned long long*)(ws + WS_CAND);
    int* cnt = (int*)(ws + WS_CNT);
    int* quant = (int*)(ws + WS_QUANT);
    int* sel_m = (int*)(ws + WS_SELM);
    float* sel_s = (float*)(ws + WS_SELS);
    float4* cb = (float4*)(ws + WS_CB);
    int* det_k = (int*)(ws + WS_DETK);

    k_stage1<<<NB * NBLK, 256, 0, stream>>>(logits, qlog, reg, props, cand, cnt,
                                            quant);
    k_fused<<<NB, 1024, 0, stream>>>(cand, cnt, reg, props, sel_m, sel_s, cb,
                                     det_k);
    k_final<<<NB * NDET, 256, 0, stream>>>(feats, quant, sel_m, sel_s, cb, det_k,
                                           out);
}

// Round 4
// 294.829 us; speedup vs baseline: 6.3381x; 1.0333x over previous
//
#include <hip/hip_runtime.h>
#include <math.h>

// Problem constants
#define NB 16
#define NR 2048
#define NC 81
#define NQ 65
#define ND 1024
#define NK 1024
#define NDET 100
#define NBLK 512           // stage1 blocks per image (4 rows each)
#define BSLOT 64           // candidate slots per stage1 block
#define HBINS 5184         // 64*81 >= 5121 used bins
#define CH 256             // fast-path sort chunk (need only first ~105 in order)
#define L2CAP 384          // top-chunk list capacity (CH + boundary-bin slack)
#define LRCAP 1536         // rest-list capacity (~768 + slack for benchmark data)
#define BBC 4.135166556742356f  // log(1000/16) as f32

// Output layout (floats), concatenated in reference return order
#define O_BOX   0
#define O_SCORE (NB*NDET*4)
#define O_LABEL (O_SCORE + NB*NDET)
#define O_QUANT (O_LABEL + NB*NDET)
#define O_FEAT  (O_QUANT + NB*NDET)
#define O_VALID (O_FEAT + (size_t)NB*NDET*ND)

// Workspace layout (bytes)
#define WS_CAND  ((size_t)0)                          // NB*NBLK*BSLOT u64 = 4 MB
#define WS_GHIST (WS_CAND + (size_t)NB*NBLK*BSLOT*8)  // NB*HBINS u32 (memset 0)
#define WS_DETCB (WS_GHIST + (size_t)NB*HBINS*4)      // NB*NDET float4
#define WS_DETM  (WS_DETCB + (size_t)NB*NDET*16)      // NB*NDET int
#define WS_DETS  (WS_DETM + (size_t)NB*NDET*4)        // NB*NDET float
#define WS_CNT   (WS_DETS + (size_t)NB*NDET*4)        // NB*NBLK int

__device__ __forceinline__ float4 decode_box(float4 d, float pw, float ph,
                                             float pcx, float pcy) {
    float dx = d.x / 10.0f, dy = d.y / 10.0f;
    float dw = fminf(d.z / 5.0f, BBC), dh = fminf(d.w / 5.0f, BBC);
    float cx = dx * pw + pcx, cy = dy * ph + pcy;
    float w = expf(dw) * pw, h = expf(dh) * ph;
    float4 r;
    r.x = fminf(fmaxf(cx - 0.5f * w, 0.0f), 640.0f);
    r.y = fminf(fmaxf(cy - 0.5f * h, 0.0f), 640.0f);
    r.z = fminf(fmaxf(cx + 0.5f * w, 0.0f), 640.0f);
    r.w = fminf(fmaxf(cy + 0.5f * h, 0.0f), 640.0f);
    return r;
}

// Stage 1: one wave per row, 4 rows per block. Zero returning-atomics.
// Also builds the per-image score histogram via fire-and-forget global atomics
// (no return value -> pipelined; spread over 16*5184 addresses).
// Quantity argmax REMOVED (deferred to k_final for the <=100 winner rows).
__global__ __launch_bounds__(256) void k_stage1(
    const float* __restrict__ logits, const float* __restrict__ reg,
    const float* __restrict__ props, unsigned long long* __restrict__ cand,
    int* __restrict__ cnt, unsigned int* __restrict__ ghist) {
    __shared__ unsigned long long sl[BSLOT];
    __shared__ int scnt;
    int b = blockIdx.x >> 9;
    int blk = blockIdx.x & (NBLK - 1);
    int wid = threadIdx.x >> 6;
    int lane = threadIdx.x & 63;
    int r = blk * 4 + wid;
    int row = b * NR + r;
    if (threadIdx.x == 0) scnt = 0;
    __syncthreads();

    const float* Lrow = logits + (size_t)row * NC;
    float v0 = Lrow[lane];
    float v1 = (lane < NC - 64) ? Lrow[64 + lane] : -1e30f;
    float mx = fmaxf(v0, v1);
    #pragma unroll
    for (int o = 32; o; o >>= 1) mx = fmaxf(mx, __shfl_xor(mx, o));
    float e = expf(v0 - mx) + ((lane < NC - 64) ? expf(v1 - mx) : 0.0f);
    float sm = e;
    #pragma unroll
    for (int o = 32; o; o >>= 1) sm += __shfl_xor(sm, o);
    // conservative logit-space threshold; exact p>0.05 re-check for survivors
    float thr_lo = mx + logf(0.05f * sm) - 0.01f;

    const float* P = props + (size_t)row * 4;
    float p0 = P[0], p1 = P[1], p2 = P[2], p3 = P[3];
    float pw = p2 - p0, ph = p3 - p1;
    float pcx = p0 + 0.5f * pw, pcy = p1 + 0.5f * ph;
    const float* G = reg + (size_t)row * (NC * 4);

    #pragma unroll
    for (int pass = 0; pass < 2; ++pass) {
        int cc = lane + pass * 64;
        if (cc < NC - 1) {
            int c = cc + 1;
            float lc = Lrow[c];
            if (lc > thr_lo) {
                float p = expf(lc - mx) / sm;          // exact, matches reference
                float4 d = *(const float4*)(G + 4 * c);
                float4 bx = decode_box(d, pw, ph, pcx, pcy);
                float bw = bx.z - bx.x, bh = bx.w - bx.y;
                if (p > 0.05f && bw >= 0.01f && bh >= 0.01f) {
                    int m = r * 80 + cc;
                    int pos = atomicAdd(&scnt, 1);     // LDS atomic, cheap
                    if (pos < BSLOT) {
                        sl[pos] = ((unsigned long long)__float_as_uint(p) << 32) |
                                  (unsigned)(~(unsigned)m);
                        unsigned bin = (__float_as_uint(p) - 0x3D000000u) >> 13;
                        atomicAdd(&ghist[b * HBINS + bin], 1u);  // fire-and-forget
                    }
                }
            }
        }
    }
    __syncthreads();
    int n = scnt < BSLOT ? scnt : BSLOT;
    unsigned long long* dst = cand + ((size_t)b * NBLK + blk) * BSLOT;
    for (int i = threadIdx.x; i < n; i += 256) dst[i] = sl[i];
    if (threadIdx.x == 0) cnt[b * NBLK + blk] = n;
}

// Fused select+decode+NMS: one 1024-thread block per image, ~8 barriers total.
// Top-CH chunk rank-sorted (1 barrier) -> NMS early-exits at NDET accepted.
// Exact-correct fallback (sort the rest, decode on the fly) for the
// astronomically-rare case of >CH-NDET suppressions in the top chunk.
__global__ __launch_bounds__(1024) void k_fused(
    const unsigned long long* __restrict__ cand, const int* __restrict__ cnt,
    const unsigned int* __restrict__ ghist,
    const float* __restrict__ reg, const float* __restrict__ props,
    int* __restrict__ det_m, float* __restrict__ det_s,
    float4* __restrict__ det_cb) {
    __shared__ union {                       // hist dead after cut-find;
        unsigned int hist[HBINS];            // sortedRest used only in fallback
        unsigned long long sortedRest[LRCAP];
    } u;
    __shared__ unsigned long long list2[L2CAP], sorted2[L2CAP];
    __shared__ unsigned long long listRest[LRCAP];
    __shared__ float4 boff[L2CAP], bclip[L2CAP];
    __shared__ int scn[NBLK];
    __shared__ int s_c2, s_cR, s_b1, s_b2, s_A, s_need;
    int b = blockIdx.x, tid = threadIdx.x;
    const unsigned long long* cnd = cand + (size_t)b * NBLK * BSLOT;

    for (int i = tid; i < HBINS; i += 1024) u.hist[i] = ghist[b * HBINS + i];
    if (tid < NBLK) scn[tid] = cnt[b * NBLK + tid];
    if (tid == 0) { s_c2 = 0; s_cR = 0; s_b1 = 0; s_b2 = 0; s_A = 0; s_need = 0; }
    __syncthreads();

    // cut bins for top-NK (b1) and top-CH (b2); wave 0 only
    if (tid < 64) {
        int lane = tid, base = lane * 81;
        unsigned partial = 0;
        for (int j = 0; j < 81; ++j) partial += u.hist[base + j];
        unsigned incl = partial;
        #pragma unroll
        for (int o = 1; o < 64; o <<= 1) {
            unsigned t = __shfl_up(incl, o);
            if (lane >= o) incl += t;
        }
        unsigned total = __shfl(incl, 63);
        unsigned suffix = total - incl;
        if (suffix < NK && suffix + partial >= NK) {
            unsigned A = suffix;
            for (int bb = base + 80; bb >= base; --bb) {
                unsigned An = A + u.hist[bb];
                if (An >= NK) { s_b1 = bb; break; }
                A = An;
            }
        }
        if (suffix < CH && suffix + partial >= CH) {
            unsigned A = suffix;
            for (int bb = base + 80; bb >= base; --bb) {
                unsigned An = A + u.hist[bb];
                if (An >= CH) { s_b2 = bb; break; }
                A = An;
            }
        }
    }
    __syncthreads();
    int b1 = s_b1, b2 = s_b2;

    // collect: top bins -> list2 (to sort now), middle bins -> listRest (lazy)
    for (int i = tid; i < NBLK * BSLOT; i += 1024) {
        if ((i & (BSLOT - 1)) < scn[i >> 6]) {
            unsigned long long key = cnd[i];
            int bin = (int)(((unsigned)(key >> 32) - 0x3D000000u) >> 13);
            if (bin >= b2) {
                int p = atomicAdd(&s_c2, 1);
                if (p < L2CAP) list2[p] = key;
            } else if (bin >= b1) {
                int p = atomicAdd(&s_cR, 1);
                if (p < LRCAP) listRest[p] = key;
            }
        }
    }
    __syncthreads();
    int T2 = s_c2 < L2CAP ? s_c2 : L2CAP;
    int TR = s_cR < LRCAP ? s_cR : LRCAP;
    int S = T2 + TR;
    int cap = S < NK ? S : NK;     // reference feeds exactly min(V,1024) to NMS
    int limit1 = T2 < cap ? T2 : cap;

    // rank-sort list2: keys unique (m in low bits); LDS broadcast reads; 1 barrier
    if (tid < T2) {
        unsigned long long k0 = list2[tid];
        int rk = 0;
        for (int j = 0; j < T2; ++j) rk += (list2[j] > k0);
        sorted2[rk] = k0;
    }
    __syncthreads();

    // decode the sorted chunk: clipped box + class-offset box -> LDS
    if (tid < limit1) {
        unsigned long long key = sorted2[tid];
        int m = (int)(~(unsigned)key);
        int r = m / 80, c = m - r * 80 + 1;
        size_t row = (size_t)b * NR + r;
        float4 P = *(const float4*)(props + row * 4);
        float pw = P.z - P.x, ph = P.w - P.y;
        float pcx = P.x + 0.5f * pw, pcy = P.y + 0.5f * ph;
        float4 d = *(const float4*)(reg + row * (NC * 4) + 4 * c);
        float4 bx = decode_box(d, pw, ph, pcx, pcy);
        bclip[tid] = bx;
        float off = (float)c * 641.0f;
        float4 o = {bx.x + off, bx.y + off, bx.z + off, bx.w + off};
        boff[tid] = o;
    }
    __syncthreads();

    // greedy NMS, wave 0; accepted boxes live in lanes (a0: 0-63, a1: 64-99)
    int lane = tid & 63;
    float4 a0 = {0, 0, 0, 0}, a1 = {0, 0, 0, 0};
    int A = 0;
    if (tid < 64) {
        unsigned long long nk_ = (limit1 > 0) ? sorted2[0] : 0ull;
        float4 nb_ = (limit1 > 0) ? boff[0] : a0;
        for (int t = 0; t < limit1; ++t) {
            unsigned long long keyt = nk_;
            float4 bt = nb_;
            if (t + 1 < limit1) { nk_ = sorted2[t + 1]; nb_ = boff[t + 1]; }
            float areaB = (bt.z - bt.x) * (bt.w - bt.y);
            float areaA0 = (a0.z - a0.x) * (a0.w - a0.y);
            float ltx = fmaxf(a0.x, bt.x), lty = fmaxf(a0.y, bt.y);
            float rbx = fminf(a0.z, bt.z), rby = fminf(a0.w, bt.w);
            float in0 = fmaxf(rbx - ltx, 0.0f) * fmaxf(rby - lty, 0.0f);
            bool sup = (lane < A) && (in0 / (areaA0 + areaB - in0 + 1e-9f) > 0.5f);
            if (A > 64) {
                float areaA1 = (a1.z - a1.x) * (a1.w - a1.y);
                float l1 = fmaxf(a1.x, bt.x), t1 = fmaxf(a1.y, bt.y);
                float r1 = fminf(a1.z, bt.z), b1f = fminf(a1.w, bt.w);
                float in1 = fmaxf(r1 - l1, 0.0f) * fmaxf(b1f - t1, 0.0f);
                sup |= (lane + 64 < A) &&
                       (in1 / (areaA1 + areaB - in1 + 1e-9f) > 0.5f);
            }
            if (!__any((int)sup)) {
                if (lane == (A & 63)) { if (A < 64) a0 = bt; else a1 = bt; }
                if (lane == 0) {
                    det_m[b * NDET + A] = (int)(~(unsigned)keyt);
                    det_s[b * NDET + A] = __uint_as_float((unsigned)(keyt >> 32));
                    det_cb[b * NDET + A] = bclip[t];
                }
                ++A;
                if (A == NDET) break;
            }
        }
        if (tid == 0) { s_A = A; s_need = (A < NDET && limit1 < cap) ? 1 : 0; }
    }
    __syncthreads();

    if (s_need) {   // rare exact-correct fallback: sort + stream the rest
        for (int t0 = tid; t0 < TR; t0 += 1024) {
            unsigned long long k0 = listRest[t0];
            int rk = 0;
            for (int j = 0; j < TR; ++j) rk += (listRest[j] > k0);
            u.sortedRest[rk] = k0;
        }
        __syncthreads();
        if (tid < 64) {
            int nrest = cap - limit1;    // cap <= S = T2 + TR -> nrest <= TR
            for (int t = 0; t < nrest && A < NDET; ++t) {
                unsigned long long keyt = u.sortedRest[t];
                int m = (int)(~(unsigned)keyt);
                int r = m / 80, c = m - r * 80 + 1;
                size_t row = (size_t)b * NR + r;
                float4 P = *(const float4*)(props + row * 4);
                float pw = P.z - P.x, ph = P.w - P.y;
                float pcx = P.x + 0.5f * pw, pcy = P.y + 0.5f * ph;
                float4 d = *(const float4*)(reg + row * (NC * 4) + 4 * c);
                float4 bx = decode_box(d, pw, ph, pcx, pcy);
                float off = (float)c * 641.0f;
                float4 bt = {bx.x + off, bx.y + off, bx.z + off, bx.w + off};
                float areaB = (bt.z - bt.x) * (bt.w - bt.y);
                float areaA0 = (a0.z - a0.x) * (a0.w - a0.y);
                float ltx = fmaxf(a0.x, bt.x), lty = fmaxf(a0.y, bt.y);
                float rbx = fminf(a0.z, bt.z), rby = fminf(a0.w, bt.w);
                float in0 = fmaxf(rbx - ltx, 0.0f) * fmaxf(rby - lty, 0.0f);
                bool sup = (lane < A) &&
                           (in0 / (areaA0 + areaB - in0 + 1e-9f) > 0.5f);
                if (A > 64) {
                    float areaA1 = (a1.z - a1.x) * (a1.w - a1.y);
                    float l1 = fmaxf(a1.x, bt.x), t1 = fmaxf(a1.y, bt.y);
                    float r1 = fminf(a1.z, bt.z), b1f = fminf(a1.w, bt.w);
                    float in1 = fmaxf(r1 - l1, 0.0f) * fmaxf(b1f - t1, 0.0f);
                    sup |= (lane + 64 < A) &&
                           (in1 / (areaA1 + areaB - in1 + 1e-9f) > 0.5f);
                }
                if (!__any((int)sup)) {
                    if (lane == (A & 63)) { if (A < 64) a0 = bt; else a1 = bt; }
                    if (lane == 0) {
                        det_m[b * NDET + A] = m;
                        det_s[b * NDET + A] =
                            __uint_as_float((unsigned)(keyt >> 32));
                        det_cb[b * NDET + A] = bx;
                    }
                    ++A;
                }
            }
            if (tid == 0) s_A = A;
        }
        __syncthreads();
    }
    for (int d = s_A + tid; d < NDET; d += 1024) det_m[b * NDET + d] = -1;
}

// Final gather: box/score/label/valid from det arrays, quantity argmax for the
// winner row (wave 0), feature row copy (all 256 threads).
__global__ __launch_bounds__(256) void k_final(
    const float* __restrict__ feats, const float* __restrict__ qlog,
    const int* __restrict__ det_m, const float* __restrict__ det_s,
    const float4* __restrict__ det_cb, float* __restrict__ out) {
    int bd = blockIdx.x;
    int b = bd / NDET;
    int t = threadIdx.x;
    int m = det_m[bd];
    float4* of = (float4*)(out + O_FEAT + (size_t)bd * ND);
    if (m >= 0) {
        int r = m / 80, c = m - r * 80 + 1;
        size_t row = (size_t)b * NR + r;
        if (t == 0) {
            ((float4*)(out + O_BOX))[bd] = det_cb[bd];
            out[O_SCORE + bd] = det_s[bd];
            out[O_LABEL + bd] = (float)c;
            out[O_VALID + bd] = 1.0f;
        }
        if (t < 64) {   // quantity argmax, first-index tiebreak
            const float* Qrow = qlog + row * NQ;
            float qv = Qrow[t];
            int qi = t;
            if (t == 0) {
                float q64 = Qrow[64];
                if (q64 > qv) { qv = q64; qi = 64; }
            }
            #pragma unroll
            for (int o = 32; o; o >>= 1) {
                float ov = __shfl_xor(qv, o);
                int oi = __shfl_xor(qi, o);
                if (ov > qv || (ov == qv && oi < qi)) { qv = ov; qi = oi; }
            }
            if (t == 0) out[O_QUANT + bd] = (float)qi;
        }
        const float4* f = (const float4*)(feats + row * ND);
        of[t] = f[t];
    } else {
        if (t == 0) {
            float4 z = {0, 0, 0, 0};
            ((float4*)(out + O_BOX))[bd] = z;
            out[O_SCORE + bd] = 0.0f;
            out[O_LABEL + bd] = 0.0f;
            out[O_QUANT + bd] = 0.0f;
            out[O_VALID + bd] = 0.0f;
        }
        float4 z = {0, 0, 0, 0};
        of[t] = z;
    }
}

extern "C" void kernel_launch(void* const* d_in, const int* in_sizes, int n_in,
                              void* d_out, int out_size, void* d_ws, size_t ws_size,
                              hipStream_t stream) {
    const float* logits = (const float*)d_in[0];
    const float* qlog   = (const float*)d_in[1];
    const float* feats  = (const float*)d_in[2];
    const float* reg    = (const float*)d_in[3];
    const float* props  = (const float*)d_in[4];
    float* out = (float*)d_out;
    char* ws = (char*)d_ws;

    unsigned long long* cand = (unsigned long long*)(ws + WS_CAND);
    unsigned int* ghist = (unsigned int*)(ws + WS_GHIST);
    float4* det_cb = (float4*)(ws + WS_DETCB);
    int* det_m = (int*)(ws + WS_DETM);
    float* det_s = (float*)(ws + WS_DETS);
    int* cnt = (int*)(ws + WS_CNT);

    hipMemsetAsync(ghist, 0, (size_t)NB * HBINS * 4, stream);
    k_stage1<<<NB * NBLK, 256, 0, stream>>>(logits, reg, props, cand, cnt, ghist);
    k_fused<<<NB, 1024, 0, stream>>>(cand, cnt, ghist, reg, props, det_m, det_s,
                                     det_cb);
    k_final<<<NB * NDET, 256, 0, stream>>>(feats, qlog, det_m, det_s, det_cb, out);
}